// Round 1
// 6708.136 us; speedup vs baseline: 1.0167x; 1.0167x over previous
//
#include <hip/hip_runtime.h>

#define N_NODES   500
#define N_EDGE_IN 2000
#define N_EDGE_TT 2500
#define VD        1000
#define STEPS     100
#define HID       8
#define NBLK      63
#define TPB       1024

// ---------------------------------------------------------------------------
// Workspace layout (bytes):
//   zA    [0, 400000)          100000 floats
//   es    [400000, 410000)     2500 int
//   ed    [410000, 420000)     2500 int
//   ew    [420000, 430000)     2500 float
//   cnt   [430080]             barrier arrival counter (monotonic per launch)
//   gen   [430208]             (unused this revision; kept for layout stability)
// ---------------------------------------------------------------------------

// Kernel A: GCN norm -> edge list (src, dst, weight) incl. self loops; init barrier.
__global__ void prep_edges(const int* __restrict__ ei, int* __restrict__ es,
                           int* __restrict__ ed, float* __restrict__ ew,
                           int* cnt, int* gen) {
    __shared__ float deg[N_NODES];
    __shared__ float dis[N_NODES];
    int tid = threadIdx.x;
    if (tid == 0) { *cnt = 0; *gen = 0; }
    for (int i = tid; i < N_NODES; i += 256) deg[i] = 1.0f;   // self loop
    __syncthreads();
    for (int e = tid; e < N_EDGE_IN; e += 256)
        atomicAdd(&deg[ei[N_EDGE_IN + e]], 1.0f);
    __syncthreads();
    for (int i = tid; i < N_NODES; i += 256) dis[i] = 1.0f / sqrtf(deg[i]);
    __syncthreads();
    for (int e = tid; e < N_EDGE_IN; e += 256) {
        int s = ei[e], d = ei[N_EDGE_IN + e];
        es[e] = s; ed[e] = d; ew[e] = dis[s] * dis[d];
    }
    for (int i = tid; i < N_NODES; i += 256) {
        es[N_EDGE_IN + i] = i; ed[N_EDGE_IN + i] = i; ew[N_EDGE_IN + i] = dis[i] * dis[i];
    }
}

// Kernel B: zA[t][j] = dot(z, A[t][j]) + b[t][j]  (fully parallel, HBM-bound)
__global__ __launch_bounds__(256) void za_kernel(const float* __restrict__ z,
                                                 const float* __restrict__ A,
                                                 const float* __restrict__ b,
                                                 float* __restrict__ zA) {
    __shared__ float4 zs[VD / 4];
    int tid = threadIdx.x;
    for (int i = tid; i < VD / 4; i += 256) zs[i] = ((const float4*)z)[i];
    __syncthreads();
    int wid = tid >> 6, lane = tid & 63;
    size_t row = (size_t)blockIdx.x * 4 + wid;
    if (row >= (size_t)STEPS * VD) return;
    const float4* Arow = (const float4*)(A + row * VD);
    float sum = 0.0f;
    for (int idx = lane; idx < VD / 4; idx += 64) {
        float4 a = Arow[idx]; float4 zz = zs[idx];
        sum += a.x * zz.x + a.y * zz.y + a.z * zz.z + a.w * zz.w;
    }
    for (int off = 32; off > 0; off >>= 1) sum += __shfl_down(sum, off, 64);
    if (lane == 0) zA[row] = sum + b[row];
}

// ---------------------------------------------------------------------------
// Kernel C: 100 sequential steps. 63 blocks x 1024 threads, cooperative.
// Every block computes the GNN redundantly in its own LDS (no producer wait);
// each of its 16 waves owns one row of Bm[t] prefetched into 16 VGPRs/lane.
//
// Cross-block exchange of v (4 KB/step) uses agent-scope coherent (sc0/sc1)
// atomic stores/loads ONLY -- no __threadfence (buffer_wbl2 + buffer_inv L2
// maintenance) anywhere in the step loop, and the barrier is a monotonic
// RELAXED counter (no ACQ_REL fence baggage, no generation reset hazard).
// Visibility argument:
//   - each wave's sc1 store of its v row is acked at the coherence point
//     before that wave passes __syncthreads (compiler emits s_waitcnt
//     vmcnt(0) before s_barrier);
//   - the arrival fetch_add (sc1 RMW) is issued by tid 0 after the barrier;
//   - readers issue sc1 loads of v only after observing the full arrival
//     count (control dep + sched_barrier(0) pin), so they read the
//     coherence point after all writes landed. Read-only tensors (Bm, zA,
//     W, edge lists) keep normal cached loads and now stay L2-warm.
// ---------------------------------------------------------------------------
__global__ __launch_bounds__(TPB) void step_kernel(
    const float* __restrict__ Bm, const float* __restrict__ W,
    const float* __restrict__ bW, const float* __restrict__ lng,
    const float* __restrict__ lnb, const float* __restrict__ zA,
    const int* __restrict__ esg, const int* __restrict__ edg,
    const float* __restrict__ ewg, int* cnt, int* gen, float* __restrict__ out)
{
    __shared__ float X[2 * N_NODES];
    __shared__ float agg[2 * N_NODES];
    __shared__ __align__(16) float uL[1024];
    __shared__ float pw[HID * 16];
    __shared__ int   esh[N_EDGE_TT];
    __shared__ int   edh[N_EDGE_TT];
    __shared__ float ewh[N_EDGE_TT];

    const int tid  = threadIdx.x;
    const int bid  = blockIdx.x;
    const int wid  = tid >> 6;
    const int lane = tid & 63;
    const int r    = bid * 16 + wid;        // output row owned by this wave
    float* vs = out + VD;                   // vs[t] = vs + t*1000

    for (int e = tid; e < N_EDGE_TT; e += TPB) { esh[e] = esg[e]; edh[e] = edg[e]; ewh[e] = ewg[e]; }
    if (tid >= 1000) uL[tid] = 0.0f;        // pad (never rewritten)
    if (bid == 0 && tid < VD) vs[tid] = (tid < N_NODES) ? 0.0f : 1.0f;  // vs[0], output-only

    for (int t = 0; t < STEPS; ++t) {
        // ---- per-step GNN params -> LDS (small, L2-hot) ----
        if (tid < HID * 16) {
            int l = tid >> 4, k = tid & 15;
            size_t base = (size_t)t * HID + l;
            float v;
            if      (k < 8)  v = W  [base * 8 + k];
            else if (k < 12) v = bW [base * 4 + (k - 8)];
            else if (k < 14) v = lng[base * 2 + (k - 12)];
            else             v = lnb[base * 2 + (k - 14)];
            pw[l * 16 + k] = v;
        }
        // ---- prefetch Bm[t] row r into registers (indep of u; overlaps GNN) ----
        float4 breg[4];
        {
            const float4* row4 = (const float4*)(Bm + ((size_t)t * VD + (r < VD ? r : 0)) * VD);
            #pragma unroll
            for (int j = 0; j < 4; ++j) {
                int e = j * 256 + lane * 4;
                breg[j] = (r < VD && e < VD) ? row4[j * 64 + lane]
                                             : make_float4(0.f, 0.f, 0.f, 0.f);
            }
        }
        float za_r = (r < VD) ? zA[(size_t)t * VD + r] : 0.0f;

        // ---- load v_t -> X (interleaved channels); coherent reads ----
        if (t == 0) {
            if (tid < N_NODES) { X[2*tid] = 0.0f; X[2*tid + 1] = 1.0f; }
        } else {
            const float* v = vs + (size_t)t * VD;
            if (tid < N_NODES) {
                X[2*tid]     = __hip_atomic_load(&v[tid],           __ATOMIC_RELAXED,
                                                 __HIP_MEMORY_SCOPE_AGENT);
                X[2*tid + 1] = __hip_atomic_load(&v[N_NODES + tid], __ATOMIC_RELAXED,
                                                 __HIP_MEMORY_SCOPE_AGENT);
            }
        }
        __syncthreads();

        // ---- 8 MixHop layers, all in LDS ----
        for (int l = 0; l < HID; ++l) {
            if (tid < 2 * N_NODES) agg[tid] = 0.0f;
            __syncthreads();
            #pragma unroll
            for (int eb = 0; eb < 3; ++eb) {
                int e = eb * TPB + tid;
                if (e < N_EDGE_TT) {
                    int s = esh[e], d = edh[e]; float wt = ewh[e];
                    atomicAdd(&agg[2*d],     wt * X[2*s]);
                    atomicAdd(&agg[2*d + 1], wt * X[2*s + 1]);
                }
            }
            __syncthreads();
            if (tid < N_NODES) {
                const float* P = pw + l * 16;
                float h0 = X[2*tid], h1 = X[2*tid+1], a0 = agg[2*tid], a1 = agg[2*tid+1];
                float o0 = P[0]*h0 + P[1]*h1 + P[4]*a0 + P[5]*a1 + P[8] + P[10];
                float o1 = P[2]*h0 + P[3]*h1 + P[6]*a0 + P[7]*a1 + P[9] + P[11];
                float d0 = 0.5f * (o0 - o1);
                float rr = 1.0f / sqrtf(d0*d0 + 1e-5f);
                float n0 =  d0 * rr * P[12] + P[14];
                float n1 = -d0 * rr * P[13] + P[15];
                X[2*tid]     = (n0 > 0.0f) ? n0 : 0.01f * n0;
                X[2*tid + 1] = (n1 > 0.0f) ? n1 : 0.01f * n1;
            }
            __syncthreads();
        }

        // ---- linearize u ----
        if (tid < N_NODES) { uL[tid] = X[2*tid]; uL[N_NODES + tid] = X[2*tid + 1]; }
        __syncthreads();

        // ---- v_{t+1}[r] = Bm[t][r] . u + zA[t][r]; coherent (sc1) publish ----
        if (r < VD) {
            const float4* u4 = (const float4*)uL;
            float sum = 0.0f;
            #pragma unroll
            for (int j = 0; j < 4; ++j) {
                float4 bb = breg[j]; float4 uu = u4[j * 64 + lane];
                sum += bb.x*uu.x + bb.y*uu.y + bb.z*uu.z + bb.w*uu.w;
            }
            #pragma unroll
            for (int off = 32; off > 0; off >>= 1) sum += __shfl_down(sum, off, 64);
            if (lane == 0) {
                float val = sum + za_r;
                __hip_atomic_store(&vs[(size_t)(t + 1) * VD + r], val,
                                   __ATOMIC_RELAXED, __HIP_MEMORY_SCOPE_AGENT);
                if (t == STEPS - 1) out[r] = val;
            }
        }

        // ---- one grid barrier per step: monotonic relaxed counter ----
        // __syncthreads drains vmcnt(0) per wave => every wave's sc1 v-store
        // is coherence-point-visible before tid 0 announces arrival.
        __syncthreads();
        if (tid == 0) {
            asm volatile("s_waitcnt vmcnt(0)" ::: "memory");   // belt & braces
            (void)__hip_atomic_fetch_add(cnt, 1, __ATOMIC_RELAXED,
                                         __HIP_MEMORY_SCOPE_AGENT);
            const int target = (t + 1) * NBLK;
            while (__hip_atomic_load(cnt, __ATOMIC_RELAXED,
                                     __HIP_MEMORY_SCOPE_AGENT) < target)
                __builtin_amdgcn_s_sleep(2);
            __builtin_amdgcn_sched_barrier(0);                 // no hoisting past spin
        }
        __syncthreads();
    }
}

// ---------------------------------------------------------------------------
extern "C" void kernel_launch(void* const* d_in, const int* in_sizes, int n_in,
                              void* d_out, int out_size, void* d_ws, size_t ws_size,
                              hipStream_t stream) {
    const float* z   = (const float*)d_in[0];
    const int*   ei  = (const int*)d_in[1];
    const float* A   = (const float*)d_in[2];
    const float* Bm  = (const float*)d_in[3];
    const float* b   = (const float*)d_in[4];
    const float* W   = (const float*)d_in[5];
    const float* bW  = (const float*)d_in[6];
    const float* lng = (const float*)d_in[7];
    const float* lnb = (const float*)d_in[8];
    float* out = (float*)d_out;

    char* ws = (char*)d_ws;
    float* zA  = (float*)ws;
    int*   es  = (int*)  (ws + 400000);
    int*   ed  = (int*)  (ws + 410000);
    float* ew  = (float*)(ws + 420000);
    int*   cnt = (int*)  (ws + 430080);
    int*   gen = (int*)  (ws + 430208);

    prep_edges<<<dim3(1), dim3(256), 0, stream>>>(ei, es, ed, ew, cnt, gen);
    za_kernel<<<dim3(STEPS * VD / 4), dim3(256), 0, stream>>>(z, A, b, zA);

    void* args[] = { (void*)&Bm, (void*)&W, (void*)&bW, (void*)&lng, (void*)&lnb,
                     (void*)&zA, (void*)&es, (void*)&ed, (void*)&ew,
                     (void*)&cnt, (void*)&gen, (void*)&out };
    hipLaunchCooperativeKernel((void*)step_kernel, dim3(NBLK), dim3(TPB),
                               args, 0, stream);
}

// Round 2
// 1689.732 us; speedup vs baseline: 4.0361x; 3.9699x over previous
//
#include <hip/hip_runtime.h>

#define N_NODES   500
#define N_EDGE_IN 2000
#define VD        1000
#define STEPS     100
#define HID       8
#define NBLK      63
#define TPB       1024
#define MAXD      20   // ELL slots per node; deg = 1 self + Binom(2000,1/500) ~ Pois(4)+1, P(>20) ~ 1e-5

// ---------------------------------------------------------------------------
// Workspace layout (bytes):
//   zA      [0, 400000)        100000 floats
//   ell_idx [400000, 420000)   ushort[500*20]  slot-major: [k*500 + node]
//   ell_w   [420000, 460000)   float [500*20]  slot-major
//   cnt     @460160            barrier arrival counter (monotonic per launch)
//   gen     @460288            release generation (monotonic per launch)
// ---------------------------------------------------------------------------

// Kernel A: GCN norm -> padded ELL (per-dst incoming edges incl. self loop).
__global__ void prep_edges(const int* __restrict__ ei, unsigned short* __restrict__ eidx,
                           float* __restrict__ ew, int* cnt, int* gen) {
    __shared__ float deg[N_NODES];
    __shared__ float dis[N_NODES];
    __shared__ int   cur[N_NODES];
    int tid = threadIdx.x;
    if (tid == 0) { *cnt = 0; *gen = 0; }
    for (int i = tid; i < N_NODES; i += 256) { deg[i] = 1.0f; cur[i] = 0; }
    __syncthreads();
    for (int e = tid; e < N_EDGE_IN; e += 256)
        atomicAdd(&deg[ei[N_EDGE_IN + e]], 1.0f);
    __syncthreads();
    for (int i = tid; i < N_NODES; i += 256) dis[i] = 1.0f / sqrtf(deg[i]);
    // zero-fill ELL (padding slots contribute w=0 * X[0] = 0)
    for (int s = tid; s < N_NODES * MAXD; s += 256) { eidx[s] = 0; ew[s] = 0.0f; }
    __syncthreads();
    for (int e = tid; e < N_EDGE_IN; e += 256) {
        int s = ei[e], d = ei[N_EDGE_IN + e];
        int k = atomicAdd(&cur[d], 1);
        if (k < MAXD) { eidx[k * N_NODES + d] = (unsigned short)s; ew[k * N_NODES + d] = dis[s] * dis[d]; }
    }
    __syncthreads();
    for (int i = tid; i < N_NODES; i += 256) {
        int k = atomicAdd(&cur[i], 1);
        if (k < MAXD) { eidx[k * N_NODES + i] = (unsigned short)i; ew[k * N_NODES + i] = dis[i] * dis[i]; }
    }
}

// Kernel B: zA[t][j] = dot(z, A[t][j]) + b[t][j]  (grid-stride, HBM-bound)
__global__ __launch_bounds__(256) void za_kernel(const float* __restrict__ z,
                                                 const float* __restrict__ A,
                                                 const float* __restrict__ b,
                                                 float* __restrict__ zA) {
    __shared__ float4 zs[VD / 4];
    int tid = threadIdx.x;
    for (int i = tid; i < VD / 4; i += 256) zs[i] = ((const float4*)z)[i];
    __syncthreads();
    int wid = tid >> 6, lane = tid & 63;
    for (size_t row = (size_t)blockIdx.x * 4 + wid; row < (size_t)STEPS * VD;
         row += (size_t)gridDim.x * 4) {
        const float4* Arow = (const float4*)(A + row * VD);
        float sum = 0.0f;
        for (int idx = lane; idx < VD / 4; idx += 64) {
            float4 a = Arow[idx]; float4 zz = zs[idx];
            sum += a.x * zz.x + a.y * zz.y + a.z * zz.z + a.w * zz.w;
        }
        #pragma unroll
        for (int off = 32; off > 0; off >>= 1) sum += __shfl_down(sum, off, 64);
        if (lane == 0) zA[row] = sum + b[row];
    }
}

// ---------------------------------------------------------------------------
// Kernel C: 100 sequential steps, 63 blocks x 1024 threads, cooperative.
// Minimum-synchronization redesign:
//   - graph in per-thread REGISTERS (ELL, 20 slots): aggregation = 20
//     independent ds_read_b64 gathers + FMA. No LDS atomics at all.
//   - X double-buffered in LDS: ONE __syncthreads per layer (8), last layer
//     writes linearized uL directly (no separate linearize phase).
//   - grid barrier: tid0 fetch_add on monotonic cnt; last arriver stores
//     gen = t+1; ALL waves poll gen directly (64 lanes same addr = 1 req).
//   Per-step barriers: 10 __syncthreads + 1 poll  (was 27 + poll).
// ---------------------------------------------------------------------------
__global__ __launch_bounds__(TPB) void step_kernel(
    const float* __restrict__ Bm, const float* __restrict__ W,
    const float* __restrict__ bW, const float* __restrict__ lng,
    const float* __restrict__ lnb, const float* __restrict__ zA,
    const unsigned short* __restrict__ eidx, const float* __restrict__ ewg,
    int* cnt, int* gen, float* __restrict__ out)
{
    __shared__ float2 Xb[2][N_NODES];
    __shared__ __align__(16) float uL[1024];
    __shared__ float pw[HID * 16];

    const int tid  = threadIdx.x;
    const int bid  = blockIdx.x;
    const int wid  = tid >> 6;
    const int lane = tid & 63;
    const int r    = bid * 16 + wid;        // output row owned by this wave
    float* vs = out + VD;                   // vs[t] = vs + t*1000

    // ---- per-node edge list -> registers (once; coalesced slot-major) ----
    int   ridx[MAXD];
    float rw[MAXD];
    if (tid < N_NODES) {
        #pragma unroll
        for (int k = 0; k < MAXD; ++k) {
            ridx[k] = (int)eidx[k * N_NODES + tid];
            rw[k]   = ewg[k * N_NODES + tid];
        }
    } else {
        #pragma unroll
        for (int k = 0; k < MAXD; ++k) { ridx[k] = 0; rw[k] = 0.0f; }
    }

    if (tid >= 1000) uL[tid] = 0.0f;        // pad (never rewritten)
    if (bid == 0 && tid < VD) vs[tid] = (tid < N_NODES) ? 0.0f : 1.0f;  // vs[0]

    for (int t = 0; t < STEPS; ++t) {
        // ---- per-step GNN params -> LDS (independent of v_t; before poll) ----
        if (tid < HID * 16) {
            int l = tid >> 4, k = tid & 15;
            size_t base = (size_t)t * HID + l;
            float v;
            if      (k < 8)  v = W  [base * 8 + k];
            else if (k < 12) v = bW [base * 4 + (k - 8)];
            else if (k < 14) v = lng[base * 2 + (k - 12)];
            else             v = lnb[base * 2 + (k - 14)];
            pw[l * 16 + k] = v;
        }
        // ---- prefetch Bm[t] row r + zA (independent of v_t; overlaps GNN) ----
        float4 breg[4];
        {
            const float4* row4 = (const float4*)(Bm + ((size_t)t * VD + (r < VD ? r : 0)) * VD);
            #pragma unroll
            for (int j = 0; j < 4; ++j) {
                int e = j * 256 + lane * 4;
                breg[j] = (r < VD && e < VD) ? row4[j * 64 + lane]
                                             : make_float4(0.f, 0.f, 0.f, 0.f);
            }
        }
        float za_r = (r < VD) ? zA[(size_t)t * VD + r] : 0.0f;

        // ---- wait for v_t (all waves poll; 1 coalesced request per wave) ----
        if (t > 0) {
            while (__hip_atomic_load(gen, __ATOMIC_RELAXED,
                                     __HIP_MEMORY_SCOPE_AGENT) < t)
                __builtin_amdgcn_s_sleep(2);
            asm volatile("" ::: "memory");  // no load crosses the spin
        }

        // ---- stage v_t -> Xb[0] (coherent reads) ----
        if (tid < N_NODES) {
            if (t == 0) {
                Xb[0][tid] = make_float2(0.0f, 1.0f);
            } else {
                const float* v = vs + (size_t)t * VD;
                float c0 = __hip_atomic_load(&v[tid],           __ATOMIC_RELAXED,
                                             __HIP_MEMORY_SCOPE_AGENT);
                float c1 = __hip_atomic_load(&v[N_NODES + tid], __ATOMIC_RELAXED,
                                             __HIP_MEMORY_SCOPE_AGENT);
                Xb[0][tid] = make_float2(c0, c1);
            }
        }

        // ---- 8 MixHop layers; ONE barrier per layer; register-ELL gather ----
        for (int l = 0; l < HID; ++l) {
            __syncthreads();                 // X for this layer is ready
            if (tid < N_NODES) {
                const float4* P4 = (const float4*)(pw + l * 16);
                float4 Pa = P4[0], Pb = P4[1], Pc = P4[2], Pd = P4[3];
                const float2* Xo = Xb[l & 1];
                float2 h = Xo[tid];
                float a0 = 0.0f, a1 = 0.0f;
                #pragma unroll
                for (int k = 0; k < MAXD; ++k) {
                    float2 xs = Xo[ridx[k]];
                    a0 += rw[k] * xs.x; a1 += rw[k] * xs.y;
                }
                float o0 = Pa.x*h.x + Pa.y*h.y + Pb.x*a0 + Pb.y*a1 + Pc.x + Pc.z;
                float o1 = Pa.z*h.x + Pa.w*h.y + Pb.z*a0 + Pb.w*a1 + Pc.y + Pc.w;
                float d0 = 0.5f * (o0 - o1);
                float rr = 1.0f / sqrtf(d0*d0 + 1e-5f);
                float n0 =  d0 * rr * Pd.x + Pd.z;
                float n1 = -d0 * rr * Pd.y + Pd.w;
                n0 = (n0 > 0.0f) ? n0 : 0.01f * n0;
                n1 = (n1 > 0.0f) ? n1 : 0.01f * n1;
                if (l == HID - 1) { uL[tid] = n0; uL[N_NODES + tid] = n1; }
                else               Xb[(l + 1) & 1][tid] = make_float2(n0, n1);
            }
        }
        __syncthreads();                     // uL ready for matvec

        // ---- v_{t+1}[r] = Bm[t][r] . u + zA[t][r]; coherent (sc1) publish ----
        if (r < VD) {
            const float4* u4 = (const float4*)uL;
            float sum = 0.0f;
            #pragma unroll
            for (int j = 0; j < 4; ++j) {
                float4 bb = breg[j]; float4 uu = u4[j * 64 + lane];
                sum += bb.x*uu.x + bb.y*uu.y + bb.z*uu.z + bb.w*uu.w;
            }
            #pragma unroll
            for (int off = 32; off > 0; off >>= 1) sum += __shfl_down(sum, off, 64);
            if (lane == 0) {
                float val = sum + za_r;
                __hip_atomic_store(&vs[(size_t)(t + 1) * VD + r], val,
                                   __ATOMIC_RELAXED, __HIP_MEMORY_SCOPE_AGENT);
                if (t == STEPS - 1) out[r] = val;
            }
        }

        // ---- arrival: drain stores, one RMW per block; last arriver releases ----
        asm volatile("s_waitcnt vmcnt(0)" ::: "memory");
        __syncthreads();                     // all waves' sc1 v-stores drained
        if (tid == 0) {
            int old = __hip_atomic_fetch_add(cnt, 1, __ATOMIC_RELAXED,
                                             __HIP_MEMORY_SCOPE_AGENT);
            if (old == (t + 1) * NBLK - 1)
                __hip_atomic_store(gen, t + 1, __ATOMIC_RELAXED,
                                   __HIP_MEMORY_SCOPE_AGENT);
        }
    }
}

// ---------------------------------------------------------------------------
extern "C" void kernel_launch(void* const* d_in, const int* in_sizes, int n_in,
                              void* d_out, int out_size, void* d_ws, size_t ws_size,
                              hipStream_t stream) {
    const float* z   = (const float*)d_in[0];
    const int*   ei  = (const int*)d_in[1];
    const float* A   = (const float*)d_in[2];
    const float* Bm  = (const float*)d_in[3];
    const float* b   = (const float*)d_in[4];
    const float* W   = (const float*)d_in[5];
    const float* bW  = (const float*)d_in[6];
    const float* lng = (const float*)d_in[7];
    const float* lnb = (const float*)d_in[8];
    float* out = (float*)d_out;

    char* ws = (char*)d_ws;
    float*          zA   = (float*)ws;
    unsigned short* eidx = (unsigned short*)(ws + 400000);
    float*          ew   = (float*)(ws + 420000);
    int*            cnt  = (int*)  (ws + 460160);
    int*            gen  = (int*)  (ws + 460288);

    prep_edges<<<dim3(1), dim3(256), 0, stream>>>(ei, eidx, ew, cnt, gen);
    za_kernel<<<dim3(2048), dim3(256), 0, stream>>>(z, A, b, zA);

    void* args[] = { (void*)&Bm, (void*)&W, (void*)&bW, (void*)&lng, (void*)&lnb,
                     (void*)&zA, (void*)&eidx, (void*)&ew,
                     (void*)&cnt, (void*)&gen, (void*)&out };
    hipLaunchCooperativeKernel((void*)step_kernel, dim3(NBLK), dim3(TPB),
                               args, 0, stream);
}